// Round 2
// baseline (530.289 us; speedup 1.0000x reference)
//
#include <hip/hip_runtime.h>
#include <hip/hip_cooperative_groups.h>

namespace cg = cooperative_groups;

#define N_NODES 50000
#define N_EDGES 800000
#define N_FEATS 64
#define EB4     (N_EDGES / 4)               // 200000 int4 groups
#define NBUCK   256                          // destination buckets == grid size
#define BRANGE  196                          // nodes per bucket: 256*196 >= 50000
#define CAPB    4096                         // records per bucket (mean 3136, +17 sigma)
#define NTHR    1024
#define CHUNK   ((EB4 + NBUCK - 1) / NBUCK)  // 782 int4 groups per block
#define MAXREC  (CHUNK * 4)                  // 3128 records max per block

// Sort buffers (bucketize) and the per-bucket record cache (prep+hops) are
// never live simultaneously -> overlay them.
union SmemU {
    struct { unsigned buf[MAXREC]; unsigned adr[MAXREC]; } so;  // 25 KB
    unsigned recs_l[CAPB];                                      // 16 KB
};

// One cooperative kernel replaces memset + bucketize + prep + 3 hops.
// Block b owns bucket b (nodes [b*196, b*196+196)). grid.sync() replaces the
// 5 dispatch boundaries; dinv / own-z / records persist in LDS across phases.
__global__ void __launch_bounds__(NTHR) k_fused(
    const float* __restrict__ x, const int* __restrict__ ei,
    const float* __restrict__ w, const float* __restrict__ bptr,
    float* __restrict__ out,
    int* __restrict__ gcur, unsigned* __restrict__ recs,
    float* __restrict__ z0, float* __restrict__ z1)
{
    __shared__ SmemU u;
    __shared__ int   s_cnt[NBUCK];     // histogram -> gbase -> degree (reused)
    __shared__ int   s_off[NBUCK];
    __shared__ int   s_wsum[4];
    __shared__ int   s_total;
    __shared__ float s_dinv[BRANGE];
    __shared__ float s_z[BRANGE];
    __shared__ float s_acc[BRANGE];

    cg::grid_group grid = cg::this_grid();
    const int t = threadIdx.x;
    const int blk = blockIdx.x;
    const int* row = ei;               // sources
    const int* col = ei + N_EDGES;     // destinations

    // ---------- phase 1: bucketize (local counting sort) ----------
    if (t == 0) gcur[blk] = 0;         // each block zeroes its own cursor
    if (t < NBUCK) s_cnt[t] = 0;
    __syncthreads();

    const int g = blk * CHUNK + t;
    const bool valid = (t < CHUNK) && (g < EB4);
    int4 c4, r4;
    int bk0, bk1, bk2, bk3, rk0, rk1, rk2, rk3;
    if (valid) {
        c4 = ((const int4*)col)[g];
        r4 = ((const int4*)row)[g];
        bk0 = c4.x / BRANGE; rk0 = atomicAdd(&s_cnt[bk0], 1);
        bk1 = c4.y / BRANGE; rk1 = atomicAdd(&s_cnt[bk1], 1);
        bk2 = c4.z / BRANGE; rk2 = atomicAdd(&s_cnt[bk2], 1);
        bk3 = c4.w / BRANGE; rk3 = atomicAdd(&s_cnt[bk3], 1);
    }
    __syncthreads();

    // 256-entry exclusive prefix sum (4 waves, shuffle scan)
    if (t < NBUCK) {
        const int lane = t & 63;
        const int cnt = s_cnt[t];
        int val = cnt;
        #pragma unroll
        for (int d = 1; d < 64; d <<= 1) {
            int tmp = __shfl_up(val, d);
            if (lane >= d) val += tmp;
        }
        if (lane == 63) s_wsum[t >> 6] = val;
        s_off[t] = val - cnt;
    }
    __syncthreads();
    if (t < NBUCK) {
        const int w4 = t >> 6;
        int base = 0;
        #pragma unroll
        for (int i = 0; i < 3; i++) if (i < w4) base += s_wsum[i];
        s_off[t] += base;
        if (t == 0) s_total = s_wsum[0] + s_wsum[1] + s_wsum[2] + s_wsum[3];
    }
    __syncthreads();

    grid.sync();   // all blocks' gcur zeroed before any reservation

    // reserve contiguous global runs; reuse s_cnt as per-bucket global base
    if (t < NBUCK) {
        const int cnt = s_cnt[t];
        s_cnt[t] = cnt ? atomicAdd(&gcur[t], cnt) : 0;
    }
    __syncthreads();

    // scatter records into LDS bucket-major with final global addresses
    if (valid) {
        const int cc[4] = {c4.x, c4.y, c4.z, c4.w};
        const int rr[4] = {r4.x, r4.y, r4.z, r4.w};
        const int bb[4] = {bk0, bk1, bk2, bk3};
        const int kk[4] = {rk0, rk1, rk2, rk3};
        #pragma unroll
        for (int i = 0; i < 4; i++) {
            const int b = bb[i];
            const int p = s_off[b] + kk[i];
            const int slot = s_cnt[b] + kk[i];
            u.so.buf[p] = ((unsigned)(cc[i] - b * BRANGE) << 16) | (unsigned)rr[i];
            u.so.adr[p] = (slot < CAPB) ? (unsigned)(b * CAPB + slot) : 0xFFFFFFFFu;
        }
    }
    __syncthreads();

    // coalesced stream-out (per-bucket runs of consecutive addresses)
    const int total = s_total;
    for (int p = t; p < total; p += NTHR) {
        const unsigned a = u.so.adr[p];
        if (a != 0xFFFFFFFFu) recs[a] = u.so.buf[p];
    }

    __threadfence();
    grid.sync();   // all records globally visible

    // ---------- phase 2: prep (degree + dinv + z0 matvec) ----------
    const int sz = min(gcur[blk], CAPB);
    if (t < BRANGE) s_cnt[t] = 0;      // reuse as degree counter
    __syncthreads();

    // pull own bucket's records into LDS once (reused by all 3 hops),
    // counting degrees on the fly
    const uint4* rb4 = (const uint4*)(recs + (size_t)blk * CAPB);
    const int szw = (sz + 3) >> 2;
    for (int e = t; e < szw; e += NTHR) {
        const uint4 r = rb4[e];
        ((uint4*)u.recs_l)[e] = r;
        const int b4 = e << 2;
        if (b4 + 0 < sz) atomicAdd(&s_cnt[r.x >> 16], 1);
        if (b4 + 1 < sz) atomicAdd(&s_cnt[r.y >> 16], 1);
        if (b4 + 2 < sz) atomicAdd(&s_cnt[r.z >> 16], 1);
        if (b4 + 3 < sz) atomicAdd(&s_cnt[r.w >> 16], 1);
    }
    __syncthreads();

    if (t < BRANGE) s_dinv[t] = rsqrtf((float)(s_cnt[t] + 1));  // +1 self loop
    __syncthreads();

    // z0 = dinv * (X @ W^T): 4 lanes per node, float4 each, shuffle reduce
    const int ln = t >> 2;
    const int pp = t & 3;
    const int node = blk * BRANGE + ln;
    if (ln < BRANGE && node < N_NODES) {
        const float4* xr = (const float4*)(x + (size_t)node * N_FEATS + pp * 16);
        const float4* wr = (const float4*)(w + pp * 16);
        float a = 0.0f;
        #pragma unroll
        for (int k = 0; k < 4; k++) {
            const float4 v = xr[k];
            const float4 q = wr[k];
            a += v.x * q.x + v.y * q.y + v.z * q.z + v.w * q.w;
        }
        a += __shfl_xor(a, 1);
        a += __shfl_xor(a, 2);
        if (pp == 0) {
            const float zv = s_dinv[ln] * a;
            s_z[ln] = zv;              // own-node z stays in LDS
            z0[node] = zv;             // global copy for other blocks' gathers
        }
    }
    __threadfence();
    grid.sync();   // z0 visible everywhere

    // ---------- phase 3: three hops ----------
    const float* zin = z0;
    float* zout = z1;
    const int sz4 = sz >> 2;
    #pragma unroll 1
    for (int hop = 0; hop < 3; ++hop) {
        if (t < BRANGE) s_acc[t] = 0.0f;
        __syncthreads();

        const uint4* rl4 = (const uint4*)u.recs_l;
        for (int e = t; e < sz4; e += NTHR) {
            const uint4 r = rl4[e];
            const float v0 = zin[r.x & 0xFFFFu];
            const float v1 = zin[r.y & 0xFFFFu];
            const float v2 = zin[r.z & 0xFFFFu];
            const float v3 = zin[r.w & 0xFFFFu];
            atomicAdd(&s_acc[r.x >> 16], v0);
            atomicAdd(&s_acc[r.y >> 16], v1);
            atomicAdd(&s_acc[r.z >> 16], v2);
            atomicAdd(&s_acc[r.w >> 16], v3);
        }
        if (t < (sz & 3)) {
            const unsigned r = u.recs_l[(sz4 << 2) + t];
            atomicAdd(&s_acc[r >> 16], zin[r & 0xFFFFu]);
        }
        __syncthreads();

        if (t < BRANGE) {
            const int nd = blk * BRANGE + t;
            if (nd < N_NODES) {
                const float d = s_dinv[t];
                const float v = s_z[t] + s_acc[t];
                if (hop == 2) {
                    out[nd] = d * v + bptr[0];
                } else {
                    const float nz = d * d * v;
                    s_z[t] = nz;
                    zout[nd] = nz;
                }
            }
        }
        if (hop < 2) {
            __threadfence();
            grid.sync();               // zout complete before next gather
            const float* tmp = zin;
            zin = zout;
            zout = const_cast<float*>(tmp);
        }
    }
}

// ---------------- launch ----------------

extern "C" void kernel_launch(void* const* d_in, const int* in_sizes, int n_in,
                              void* d_out, int out_size, void* d_ws, size_t ws_size,
                              hipStream_t stream) {
    const float* x  = (const float*)d_in[0];   // [N, 64]
    const int*   ei = (const int*)d_in[1];     // [2, E]
    const float* W  = (const float*)d_in[2];   // [1, 64]
    const float* b  = (const float*)d_in[3];   // [1]
    float* out = (float*)d_out;                // [N]

    // ws: gcur[256] | recs[NBUCK*CAPB u32] (4 MB) | z0[N] | z1[N]
    int*      gcur = (int*)d_ws;
    unsigned* recs = (unsigned*)(gcur + NBUCK);
    float*    z0   = (float*)(recs + (size_t)NBUCK * CAPB);
    float*    z1   = z0 + N_NODES;

    void* args[] = {
        (void*)&x, (void*)&ei, (void*)&W, (void*)&b, (void*)&out,
        (void*)&gcur, (void*)&recs, (void*)&z0, (void*)&z1
    };
    hipLaunchCooperativeKernel((const void*)k_fused, dim3(NBUCK), dim3(NTHR),
                               args, 0, stream);
}

// Round 3
// 149.450 us; speedup vs baseline: 3.5483x; 3.5483x over previous
//
#include <hip/hip_runtime.h>

#define N_NODES 50000
#define N_EDGES 800000
#define N_FEATS 64
#define EB4     (N_EDGES / 4)               // 200000 int4 groups
#define NBUCK   256                          // destination buckets == grid size
#define BRANGE  196                          // nodes per bucket: 256*196 >= 50000
#define CAPB    4096                         // records per bucket (mean 3136, +17 sigma)
#define NTHR    1024
#define CHUNK   ((EB4 + NBUCK - 1) / NBUCK)  // 782 int4 groups per block
#define MAXREC  (CHUNK * 4)                  // 3128 records max per block

// Sort buffers (bucketize) and the per-bucket record cache (prep+hops) are
// never live simultaneously -> overlay them.
union SmemU {
    struct { unsigned buf[MAXREC]; unsigned adr[MAXREC]; } so;  // 25 KB
    unsigned recs_l[CAPB];                                      // 16 KB
};

// Fence-free grid barrier. Preconditions for correctness:
//  - ALL cross-block data is exchanged via agent-scope (sc1) atomics that are
//    serviced at the L3 coherence point (per-XCD L2s are not coherent).
//  - __syncthreads() drains each wave's vmcnt before s_barrier (HIP semantics),
//    so every sc1 store in the block is globally visible before the arrival add.
//  - Counter is monotonic (targets 256,512,...), zeroed by host-side memset.
// This avoids CG grid.sync's per-block buffer_wbl2/buffer_inv L2 walks and
// long s_sleep backoff, which measured ~70 us per sync in R1.
__device__ __forceinline__ void gbar(unsigned* bar, unsigned target) {
    __syncthreads();
    if (threadIdx.x == 0) {
        __hip_atomic_fetch_add(bar, 1u, __ATOMIC_RELAXED, __HIP_MEMORY_SCOPE_AGENT);
        while (__hip_atomic_load(bar, __ATOMIC_RELAXED, __HIP_MEMORY_SCOPE_AGENT) < target)
            __builtin_amdgcn_s_sleep(2);
    }
    __syncthreads();
}

__device__ __forceinline__ void st_agent(float* p, float v) {
    __hip_atomic_store(p, v, __ATOMIC_RELAXED, __HIP_MEMORY_SCOPE_AGENT);
}
__device__ __forceinline__ void st_agent_u(unsigned* p, unsigned v) {
    __hip_atomic_store(p, v, __ATOMIC_RELAXED, __HIP_MEMORY_SCOPE_AGENT);
}
__device__ __forceinline__ float ld_agent(const float* p) {
    return __hip_atomic_load(p, __ATOMIC_RELAXED, __HIP_MEMORY_SCOPE_AGENT);
}
__device__ __forceinline__ unsigned ld_agent_u(const unsigned* p) {
    return __hip_atomic_load(p, __ATOMIC_RELAXED, __HIP_MEMORY_SCOPE_AGENT);
}
__device__ __forceinline__ unsigned long long ld_agent_u64(const unsigned long long* p) {
    return __hip_atomic_load(p, __ATOMIC_RELAXED, __HIP_MEMORY_SCOPE_AGENT);
}

// One kernel: bucketize + prep + 3 hops, separated by 4 fence-free barriers.
// Block b owns bucket b (nodes [b*196, b*196+196)).
__global__ void __launch_bounds__(NTHR) k_fused(
    const float* __restrict__ x, const int* __restrict__ ei,
    const float* __restrict__ w, const float* __restrict__ bptr,
    float* __restrict__ out,
    unsigned* __restrict__ bars, int* __restrict__ gcur,
    unsigned* __restrict__ recs, float* __restrict__ z0, float* __restrict__ z1)
{
    __shared__ SmemU u;
    __shared__ int   s_cnt[NBUCK];     // histogram -> gbase -> degree (reused)
    __shared__ int   s_off[NBUCK];
    __shared__ int   s_wsum[4];
    __shared__ int   s_total;
    __shared__ float s_dinv[BRANGE];
    __shared__ float s_z[BRANGE];
    __shared__ float s_acc[BRANGE];

    const int t = threadIdx.x;
    const int blk = blockIdx.x;
    const int* row = ei;               // sources
    const int* col = ei + N_EDGES;     // destinations

    // ---------- phase 1: bucketize (local counting sort) ----------
    if (t < NBUCK) s_cnt[t] = 0;
    __syncthreads();

    const int g = blk * CHUNK + t;
    const bool valid = (t < CHUNK) && (g < EB4);
    int4 c4, r4;
    int bk0, bk1, bk2, bk3, rk0, rk1, rk2, rk3;
    if (valid) {
        c4 = ((const int4*)col)[g];
        r4 = ((const int4*)row)[g];
        bk0 = c4.x / BRANGE; rk0 = atomicAdd(&s_cnt[bk0], 1);
        bk1 = c4.y / BRANGE; rk1 = atomicAdd(&s_cnt[bk1], 1);
        bk2 = c4.z / BRANGE; rk2 = atomicAdd(&s_cnt[bk2], 1);
        bk3 = c4.w / BRANGE; rk3 = atomicAdd(&s_cnt[bk3], 1);
    }
    __syncthreads();

    // 256-entry exclusive prefix sum (4 waves, shuffle scan)
    if (t < NBUCK) {
        const int lane = t & 63;
        const int cnt = s_cnt[t];
        int val = cnt;
        #pragma unroll
        for (int d = 1; d < 64; d <<= 1) {
            int tmp = __shfl_up(val, d);
            if (lane >= d) val += tmp;
        }
        if (lane == 63) s_wsum[t >> 6] = val;
        s_off[t] = val - cnt;
    }
    __syncthreads();
    if (t < NBUCK) {
        const int w4 = t >> 6;
        int base = 0;
        #pragma unroll
        for (int i = 0; i < 3; i++) if (i < w4) base += s_wsum[i];
        s_off[t] += base;
        // reserve contiguous global run per bucket (gcur zeroed by host memset);
        // atomicAdd on global is device-scope -> safe without a prior barrier
        const int cnt = s_cnt[t];
        s_cnt[t] = cnt ? atomicAdd(&gcur[t], cnt) : 0;
        if (t == 0) s_total = s_wsum[0] + s_wsum[1] + s_wsum[2] + s_wsum[3];
    }
    __syncthreads();

    // scatter records into LDS bucket-major with final global addresses
    if (valid) {
        const int cc[4] = {c4.x, c4.y, c4.z, c4.w};
        const int rr[4] = {r4.x, r4.y, r4.z, r4.w};
        const int bb[4] = {bk0, bk1, bk2, bk3};
        const int kk[4] = {rk0, rk1, rk2, rk3};
        #pragma unroll
        for (int i = 0; i < 4; i++) {
            const int b = bb[i];
            const int p = s_off[b] + kk[i];
            const int slot = s_cnt[b] + kk[i];
            u.so.buf[p] = ((unsigned)(cc[i] - b * BRANGE) << 16) | (unsigned)rr[i];
            u.so.adr[p] = (slot < CAPB) ? (unsigned)(b * CAPB + slot) : 0xFFFFFFFFu;
        }
    }
    __syncthreads();

    // coalesced stream-out via sc1 stores (visible at L3 coherence point)
    const int total = s_total;
    for (int p = t; p < total; p += NTHR) {
        const unsigned a = u.so.adr[p];
        if (a != 0xFFFFFFFFu) st_agent_u(&recs[a], u.so.buf[p]);
    }

    gbar(bars, 1 * NBUCK);   // all records at L3

    // ---------- phase 2: prep (degree + dinv + z0 matvec) ----------
    const int sz = min((int)ld_agent_u((const unsigned*)&gcur[blk]), CAPB);
    if (t < BRANGE) s_cnt[t] = 0;      // reuse as degree counter
    __syncthreads();

    // pull own bucket's records into LDS once (reused by all 3 hops),
    // counting degrees on the fly; 64-bit sc1 loads (2 records each)
    const unsigned long long* rb2 =
        (const unsigned long long*)(recs + (size_t)blk * CAPB);
    const int sz2 = sz >> 1;
    for (int e = t; e < sz2; e += NTHR) {
        const unsigned long long v = ld_agent_u64(&rb2[e]);
        const unsigned r0 = (unsigned)v;
        const unsigned r1 = (unsigned)(v >> 32);
        ((unsigned long long*)u.recs_l)[e] = v;
        atomicAdd(&s_cnt[r0 >> 16], 1);
        atomicAdd(&s_cnt[r1 >> 16], 1);
    }
    if (t == 0 && (sz & 1)) {
        const unsigned r = ld_agent_u(&recs[(size_t)blk * CAPB + sz - 1]);
        u.recs_l[sz - 1] = r;
        atomicAdd(&s_cnt[r >> 16], 1);
    }
    __syncthreads();

    if (t < BRANGE) s_dinv[t] = rsqrtf((float)(s_cnt[t] + 1));  // +1 self loop
    __syncthreads();

    // z0 = dinv * (X @ W^T): 4 lanes per node, float4 each, shuffle reduce
    const int ln = t >> 2;
    const int pp = t & 3;
    const int node = blk * BRANGE + ln;
    if (ln < BRANGE && node < N_NODES) {
        const float4* xr = (const float4*)(x + (size_t)node * N_FEATS + pp * 16);
        const float4* wr = (const float4*)(w + pp * 16);
        float a = 0.0f;
        #pragma unroll
        for (int k = 0; k < 4; k++) {
            const float4 v = xr[k];
            const float4 q = wr[k];
            a += v.x * q.x + v.y * q.y + v.z * q.z + v.w * q.w;
        }
        a += __shfl_xor(a, 1);
        a += __shfl_xor(a, 2);
        if (pp == 0) {
            const float zv = s_dinv[ln] * a;
            s_z[ln] = zv;              // own-node z stays in LDS
            st_agent(&z0[node], zv);   // sc1 copy for other blocks' gathers
        }
    }

    gbar(bars, 2 * NBUCK);   // z0 at L3

    // ---------- phase 3: three hops ----------
    const float* zin = z0;
    float* zout = z1;
    const int sz4 = sz >> 2;
    #pragma unroll 1
    for (int hop = 0; hop < 3; ++hop) {
        if (t < BRANGE) s_acc[t] = 0.0f;
        __syncthreads();

        const uint4* rl4 = (const uint4*)u.recs_l;
        for (int e = t; e < sz4; e += NTHR) {
            const uint4 r = rl4[e];
            const float v0 = ld_agent(&zin[r.x & 0xFFFFu]);
            const float v1 = ld_agent(&zin[r.y & 0xFFFFu]);
            const float v2 = ld_agent(&zin[r.z & 0xFFFFu]);
            const float v3 = ld_agent(&zin[r.w & 0xFFFFu]);
            atomicAdd(&s_acc[r.x >> 16], v0);
            atomicAdd(&s_acc[r.y >> 16], v1);
            atomicAdd(&s_acc[r.z >> 16], v2);
            atomicAdd(&s_acc[r.w >> 16], v3);
        }
        if (t < (sz & 3)) {
            const unsigned r = u.recs_l[(sz4 << 2) + t];
            atomicAdd(&s_acc[r >> 16], ld_agent(&zin[r & 0xFFFFu]));
        }
        __syncthreads();

        if (t < BRANGE) {
            const int nd = blk * BRANGE + t;
            if (nd < N_NODES) {
                const float d = s_dinv[t];
                const float v = s_z[t] + s_acc[t];
                if (hop == 2) {
                    out[nd] = d * v + bptr[0];
                } else {
                    const float nz = d * d * v;
                    s_z[t] = nz;
                    st_agent(&zout[nd], nz);
                }
            }
        }
        if (hop < 2) {
            gbar(bars, (unsigned)(3 + hop) * NBUCK);  // zout at L3
            const float* tmp = zin;
            zin = zout;
            zout = const_cast<float*>(tmp);
        }
    }
}

// ---------------- launch ----------------

extern "C" void kernel_launch(void* const* d_in, const int* in_sizes, int n_in,
                              void* d_out, int out_size, void* d_ws, size_t ws_size,
                              hipStream_t stream) {
    const float* x  = (const float*)d_in[0];   // [N, 64]
    const int*   ei = (const int*)d_in[1];     // [2, E]
    const float* W  = (const float*)d_in[2];   // [1, 64]
    const float* b  = (const float*)d_in[3];   // [1]
    float* out = (float*)d_out;                // [N]

    // ws: bars[64] | gcur[256] | recs[NBUCK*CAPB u32] (4 MB) | z0[N] | z1[N]
    unsigned* bars = (unsigned*)d_ws;
    int*      gcur = (int*)(bars + 64);
    unsigned* recs = (unsigned*)(gcur + NBUCK);
    float*    z0   = (float*)(recs + (size_t)NBUCK * CAPB);
    float*    z1   = z0 + N_NODES;

    // zero barrier counters + bucket cursors (capture-safe DMA memset);
    // kernel-boundary cache flush makes these visible to the sc1 atomics
    hipMemsetAsync(bars, 0, (64 + NBUCK) * sizeof(unsigned), stream);

    void* args[] = {
        (void*)&x, (void*)&ei, (void*)&W, (void*)&b, (void*)&out,
        (void*)&bars, (void*)&gcur, (void*)&recs, (void*)&z0, (void*)&z1
    };
    hipLaunchCooperativeKernel((const void*)k_fused, dim3(NBUCK), dim3(NTHR),
                               args, 0, stream);
}

// Round 4
// 115.900 us; speedup vs baseline: 4.5754x; 1.2895x over previous
//
#include <hip/hip_runtime.h>

#define N_NODES 50000
#define N_EDGES 800000
#define N_FEATS 64
#define EB4     (N_EDGES / 4)               // 200000 int4 groups
#define NBUCK   256                          // destination buckets == grid size
#define BRANGE  196                          // nodes per bucket: 256*196 >= 50000
#define CAPB    4096                         // records per bucket (mean 3136, +17 sigma)
#define NTHR    1024
#define CHUNK   ((EB4 + NBUCK - 1) / NBUCK)  // 782 int4 groups per block
#define MAXREC  (CHUNK * 4)                  // 3128 records max per block

// Sort buffers (bucketize) and the per-bucket record cache (prep+hops) are
// never live simultaneously -> overlay them.
union SmemU {
    struct { unsigned buf[MAXREC]; unsigned adr[MAXREC]; } so;  // 25 KB
    unsigned recs_l[CAPB];                                      // 16 KB
};

// Fence-free grid barrier (R2-proven: CG grid.sync was ~70us/sync; this is ~us).
// Preconditions:
//  - ALL cross-block data moves via agent-scope (sc1) atomics serviced at the
//    L3 coherence point (per-XCD L2s are not coherent).
//  - __syncthreads() drains vmcnt before s_barrier (HIP semantics), so every
//    sc1 store in the block is globally visible before the arrival add.
//  - Counter is monotonic (targets 256,512,...), zeroed by host-side memset.
// Requires all 256 blocks co-resident: 16 waves/block, 24 VGPR, 29.7 KB LDS
// -> 2 blocks/CU capacity on 256 CUs, so a plain (non-cooperative) launch of
// 256 blocks is always fully resident; no cooperative launch needed.
__device__ __forceinline__ void gbar(unsigned* bar, unsigned target) {
    __syncthreads();
    if (threadIdx.x == 0) {
        __hip_atomic_fetch_add(bar, 1u, __ATOMIC_RELAXED, __HIP_MEMORY_SCOPE_AGENT);
        while (__hip_atomic_load(bar, __ATOMIC_RELAXED, __HIP_MEMORY_SCOPE_AGENT) < target)
            __builtin_amdgcn_s_sleep(2);
    }
    __syncthreads();
}

__device__ __forceinline__ void st_agent(float* p, float v) {
    __hip_atomic_store(p, v, __ATOMIC_RELAXED, __HIP_MEMORY_SCOPE_AGENT);
}
__device__ __forceinline__ void st_agent_u(unsigned* p, unsigned v) {
    __hip_atomic_store(p, v, __ATOMIC_RELAXED, __HIP_MEMORY_SCOPE_AGENT);
}
__device__ __forceinline__ float ld_agent(const float* p) {
    return __hip_atomic_load(p, __ATOMIC_RELAXED, __HIP_MEMORY_SCOPE_AGENT);
}
__device__ __forceinline__ unsigned ld_agent_u(const unsigned* p) {
    return __hip_atomic_load(p, __ATOMIC_RELAXED, __HIP_MEMORY_SCOPE_AGENT);
}
__device__ __forceinline__ unsigned long long ld_agent_u64(const unsigned long long* p) {
    return __hip_atomic_load(p, __ATOMIC_RELAXED, __HIP_MEMORY_SCOPE_AGENT);
}

// One kernel: bucketize + prep + 3 hops, separated by 4 fence-free barriers.
// Block b owns bucket b (nodes [b*196, b*196+196)).
__global__ void __launch_bounds__(NTHR) k_fused(
    const float* __restrict__ x, const int* __restrict__ ei,
    const float* __restrict__ w, const float* __restrict__ bptr,
    float* __restrict__ out,
    unsigned* __restrict__ bars, int* __restrict__ gcur,
    unsigned* __restrict__ recs, float* __restrict__ z0, float* __restrict__ z1)
{
    __shared__ SmemU u;
    __shared__ int   s_cnt[NBUCK];     // histogram -> gbase -> degree (reused)
    __shared__ int   s_off[NBUCK];
    __shared__ int   s_wsum[4];
    __shared__ int   s_total;
    __shared__ float s_dinv[BRANGE];
    __shared__ float s_z[BRANGE];
    __shared__ float s_acc[BRANGE];

    const int t = threadIdx.x;
    const int blk = blockIdx.x;
    const int* row = ei;               // sources
    const int* col = ei + N_EDGES;     // destinations

    // ---------- phase 1: bucketize (local counting sort) ----------
    if (t < NBUCK) s_cnt[t] = 0;
    __syncthreads();

    const int g = blk * CHUNK + t;
    const bool valid = (t < CHUNK) && (g < EB4);
    int4 c4, r4;
    int bk0, bk1, bk2, bk3, rk0, rk1, rk2, rk3;
    if (valid) {
        c4 = ((const int4*)col)[g];
        r4 = ((const int4*)row)[g];
        bk0 = c4.x / BRANGE; rk0 = atomicAdd(&s_cnt[bk0], 1);
        bk1 = c4.y / BRANGE; rk1 = atomicAdd(&s_cnt[bk1], 1);
        bk2 = c4.z / BRANGE; rk2 = atomicAdd(&s_cnt[bk2], 1);
        bk3 = c4.w / BRANGE; rk3 = atomicAdd(&s_cnt[bk3], 1);
    }
    __syncthreads();

    // 256-entry exclusive prefix sum (4 waves, shuffle scan)
    if (t < NBUCK) {
        const int lane = t & 63;
        const int cnt = s_cnt[t];
        int val = cnt;
        #pragma unroll
        for (int d = 1; d < 64; d <<= 1) {
            int tmp = __shfl_up(val, d);
            if (lane >= d) val += tmp;
        }
        if (lane == 63) s_wsum[t >> 6] = val;
        s_off[t] = val - cnt;
    }
    __syncthreads();
    if (t < NBUCK) {
        const int w4 = t >> 6;
        int base = 0;
        #pragma unroll
        for (int i = 0; i < 3; i++) if (i < w4) base += s_wsum[i];
        s_off[t] += base;
        // reserve contiguous global run per bucket (gcur zeroed by host memset);
        // plain atomicAdd on global memory is agent-scope already
        const int cnt = s_cnt[t];
        s_cnt[t] = cnt ? atomicAdd(&gcur[t], cnt) : 0;
        if (t == 0) s_total = s_wsum[0] + s_wsum[1] + s_wsum[2] + s_wsum[3];
    }
    __syncthreads();

    // scatter records into LDS bucket-major with final global addresses
    if (valid) {
        const int cc[4] = {c4.x, c4.y, c4.z, c4.w};
        const int rr[4] = {r4.x, r4.y, r4.z, r4.w};
        const int bb[4] = {bk0, bk1, bk2, bk3};
        const int kk[4] = {rk0, rk1, rk2, rk3};
        #pragma unroll
        for (int i = 0; i < 4; i++) {
            const int b = bb[i];
            const int p = s_off[b] + kk[i];
            const int slot = s_cnt[b] + kk[i];
            u.so.buf[p] = ((unsigned)(cc[i] - b * BRANGE) << 16) | (unsigned)rr[i];
            u.so.adr[p] = (slot < CAPB) ? (unsigned)(b * CAPB + slot) : 0xFFFFFFFFu;
        }
    }
    __syncthreads();

    // coalesced stream-out via sc1 stores FIRST (fire-and-forget into the
    // write queue), then the matvec loads go into flight behind them.
    const int total = s_total;
    for (int p = t; p < total; p += NTHR) {
        const unsigned a = u.so.adr[p];
        if (a != 0xFFFFFFFFu) st_agent_u(&recs[a], u.so.buf[p]);
    }

    // raw matvec (X @ W^T, no dinv yet) OVERLAPPED with stream-out + barrier
    // skew: independent of records. 4 lanes per node, float4 each, shuffle
    // reduce; result parked in s_z, scaled by dinv after degrees are known.
    const int ln = t >> 2;
    const int pp = t & 3;
    const int node = blk * BRANGE + ln;
    if (ln < BRANGE && node < N_NODES) {
        const float4* xr = (const float4*)(x + (size_t)node * N_FEATS + pp * 16);
        const float4* wr = (const float4*)(w + pp * 16);
        float a = 0.0f;
        #pragma unroll
        for (int k = 0; k < 4; k++) {
            const float4 v = xr[k];
            const float4 q = wr[k];
            a += v.x * q.x + v.y * q.y + v.z * q.z + v.w * q.w;
        }
        a += __shfl_xor(a, 1);
        a += __shfl_xor(a, 2);
        if (pp == 0) s_z[ln] = a;      // raw; dinv applied after gbar1
    }
    // zero degree counters before the barrier (shortens post-barrier path);
    // s_cnt's gbase role is dead after the scatter above
    __syncthreads();
    if (t < BRANGE) s_cnt[t] = 0;

    gbar(bars, 1 * NBUCK);   // all records at L3

    // ---------- phase 2: prep (degree + dinv + z0) ----------
    const int sz = min((int)ld_agent_u((const unsigned*)&gcur[blk]), CAPB);

    // pull own bucket's records into LDS once (reused by all 3 hops),
    // counting degrees on the fly; 64-bit sc1 loads (2 records each)
    const unsigned long long* rb2 =
        (const unsigned long long*)(recs + (size_t)blk * CAPB);
    const int sz2 = sz >> 1;
    for (int e = t; e < sz2; e += NTHR) {
        const unsigned long long v = ld_agent_u64(&rb2[e]);
        const unsigned r0 = (unsigned)v;
        const unsigned r1 = (unsigned)(v >> 32);
        ((unsigned long long*)u.recs_l)[e] = v;
        atomicAdd(&s_cnt[r0 >> 16], 1);
        atomicAdd(&s_cnt[r1 >> 16], 1);
    }
    if (t == 0 && (sz & 1)) {
        const unsigned r = ld_agent_u(&recs[(size_t)blk * CAPB + sz - 1]);
        u.recs_l[sz - 1] = r;
        atomicAdd(&s_cnt[r >> 16], 1);
    }
    __syncthreads();

    if (t < BRANGE) {
        const float d = rsqrtf((float)(s_cnt[t] + 1));  // +1 self loop
        s_dinv[t] = d;
        const int nd = blk * BRANGE + t;
        if (nd < N_NODES) {
            const float zv = d * s_z[t];
            s_z[t] = zv;               // own-node z stays in LDS
            st_agent(&z0[nd], zv);     // sc1 copy for other blocks' gathers
        }
    }

    gbar(bars, 2 * NBUCK);   // z0 at L3

    // ---------- phase 3: three hops ----------
    const float* zin = z0;
    float* zout = z1;
    const int sz4 = sz >> 2;
    #pragma unroll 1
    for (int hop = 0; hop < 3; ++hop) {
        if (t < BRANGE) s_acc[t] = 0.0f;
        __syncthreads();

        const uint4* rl4 = (const uint4*)u.recs_l;
        for (int e = t; e < sz4; e += NTHR) {
            const uint4 r = rl4[e];
            const float v0 = ld_agent(&zin[r.x & 0xFFFFu]);
            const float v1 = ld_agent(&zin[r.y & 0xFFFFu]);
            const float v2 = ld_agent(&zin[r.z & 0xFFFFu]);
            const float v3 = ld_agent(&zin[r.w & 0xFFFFu]);
            atomicAdd(&s_acc[r.x >> 16], v0);
            atomicAdd(&s_acc[r.y >> 16], v1);
            atomicAdd(&s_acc[r.z >> 16], v2);
            atomicAdd(&s_acc[r.w >> 16], v3);
        }
        if (t < (sz & 3)) {
            const unsigned r = u.recs_l[(sz4 << 2) + t];
            atomicAdd(&s_acc[r >> 16], ld_agent(&zin[r & 0xFFFFu]));
        }
        __syncthreads();

        if (t < BRANGE) {
            const int nd = blk * BRANGE + t;
            if (nd < N_NODES) {
                const float d = s_dinv[t];
                const float v = s_z[t] + s_acc[t];
                if (hop == 2) {
                    out[nd] = d * v + bptr[0];
                } else {
                    const float nz = d * d * v;
                    s_z[t] = nz;
                    st_agent(&zout[nd], nz);
                }
            }
        }
        if (hop < 2) {
            gbar(bars, (unsigned)(3 + hop) * NBUCK);  // zout at L3
            const float* tmp = zin;
            zin = zout;
            zout = const_cast<float*>(tmp);
        }
    }
}

// ---------------- launch ----------------

extern "C" void kernel_launch(void* const* d_in, const int* in_sizes, int n_in,
                              void* d_out, int out_size, void* d_ws, size_t ws_size,
                              hipStream_t stream) {
    const float* x  = (const float*)d_in[0];   // [N, 64]
    const int*   ei = (const int*)d_in[1];     // [2, E]
    const float* W  = (const float*)d_in[2];   // [1, 64]
    const float* b  = (const float*)d_in[3];   // [1]
    float* out = (float*)d_out;                // [N]

    // ws: bars[64] | gcur[256] | recs[NBUCK*CAPB u32] (4 MB) | z0[N] | z1[N]
    unsigned* bars = (unsigned*)d_ws;
    int*      gcur = (int*)(bars + 64);
    unsigned* recs = (unsigned*)(gcur + NBUCK);
    float*    z0   = (float*)(recs + (size_t)NBUCK * CAPB);
    float*    z1   = z0 + N_NODES;

    // zero barrier counters + bucket cursors (capture-safe DMA memset);
    // stream-ordered before the kernel, kernel-boundary flush makes these
    // visible to the sc1 atomics
    hipMemsetAsync(bars, 0, (64 + NBUCK) * sizeof(unsigned), stream);

    // plain launch: 256 blocks x 16 waves (24 VGPR, 29.7 KB LDS) = guaranteed
    // co-resident on 256 CUs (2 blocks/CU capacity) -> spin barrier is safe;
    // avoids hipLaunchCooperativeKernel's ~80 us per-launch overhead (R1/R2).
    k_fused<<<dim3(NBUCK), dim3(NTHR), 0, stream>>>(
        x, ei, W, b, out, bars, gcur, recs, z0, z1);
}

// Round 5
// 112.604 us; speedup vs baseline: 4.7093x; 1.0293x over previous
//
#include <hip/hip_runtime.h>

#define N_NODES 50000
#define N_EDGES 800000
#define N_FEATS 64
#define EB4     (N_EDGES / 4)               // 200000 int4 groups
#define NBUCK   256                          // destination buckets == grid size
#define BRANGE  196                          // nodes per bucket: 256*196 >= 50000
#define ZSTRIDE 208                          // BRANGE padded to 64B lines: each z line owned by ONE block
#define CAPB    4096                         // records per bucket (mean 3136, +17 sigma)
#define NTHR    1024
#define CHUNK   ((EB4 + NBUCK - 1) / NBUCK)  // 782 int4 groups per block
#define MAXREC  (CHUNK * 4)                  // 3128 records max per block
#define BARW    32                           // distributed-barrier counter count

// Sort buffers (bucketize) and the per-bucket record cache (prep+hops) are
// never live simultaneously -> overlay them.
union SmemU {
    struct { unsigned buf[MAXREC]; unsigned adr[MAXREC]; } so;  // 25 KB
    unsigned recs_l[CAPB];                                      // 16 KB
};

__device__ __forceinline__ void st_agent(float* p, float v) {
    __hip_atomic_store(p, v, __ATOMIC_RELAXED, __HIP_MEMORY_SCOPE_AGENT);
}
__device__ __forceinline__ void st_agent_u(unsigned* p, unsigned v) {
    __hip_atomic_store(p, v, __ATOMIC_RELAXED, __HIP_MEMORY_SCOPE_AGENT);
}
__device__ __forceinline__ unsigned ld_agent_u(const unsigned* p) {
    return __hip_atomic_load(p, __ATOMIC_RELAXED, __HIP_MEMORY_SCOPE_AGENT);
}
__device__ __forceinline__ unsigned long long ld_agent_u64(const unsigned long long* p) {
    return __hip_atomic_load(p, __ATOMIC_RELAXED, __HIP_MEMORY_SCOPE_AGENT);
}

// Distributed fence-free grid barrier (R3's single-counter gbar serialized 256
// atomic RMWs + 256 pollers on ONE L3 line -> est. 3-6us/barrier).
// Arrivals spread over 32 counters (blk&31 -> 8-way RMW serialization);
// lanes 0..31 of wave 0 poll all 32 with one coalesced load + shfl reduce.
// Correctness: __syncthreads() drains vmcnt before s_barrier, so all of this
// block's sc1 stores are at the coherence point before the arrival add.
// Counters are monotonic, one fresh group of 32 per barrier, host-zeroed.
__device__ __forceinline__ void gbar(unsigned* bars, int k) {
    __syncthreads();
    const int t = threadIdx.x;
    if (t == 0)
        __hip_atomic_fetch_add(&bars[k * BARW + (blockIdx.x & (BARW - 1))], 1u,
                               __ATOMIC_RELAXED, __HIP_MEMORY_SCOPE_AGENT);
    if (t < BARW) {
        unsigned s;
        do {
            __builtin_amdgcn_s_sleep(1);
            s = __hip_atomic_load(&bars[k * BARW + t],
                                  __ATOMIC_RELAXED, __HIP_MEMORY_SCOPE_AGENT);
            #pragma unroll
            for (int d = 1; d < BARW; d <<= 1)
                s += (unsigned)__shfl_xor((int)s, d);
        } while (s < NBUCK);
    }
    __syncthreads();
}

// Gather own bucket's records (in LDS) against zin (CACHED reads: zin is
// read in exactly one hop -> no stale-L2 hazard; 64B lines single-owner).
__device__ __forceinline__ void gather(const unsigned* recs_l, int sz,
                                       const float* __restrict__ zin,
                                       float* s_acc) {
    const int t = threadIdx.x;
    const int sz4 = sz >> 2;
    const uint4* rl4 = (const uint4*)recs_l;
    for (int e = t; e < sz4; e += NTHR) {
        const uint4 r = rl4[e];
        const float v0 = zin[r.x & 0xFFFFu];
        const float v1 = zin[r.y & 0xFFFFu];
        const float v2 = zin[r.z & 0xFFFFu];
        const float v3 = zin[r.w & 0xFFFFu];
        atomicAdd(&s_acc[r.x >> 16], v0);
        atomicAdd(&s_acc[r.y >> 16], v1);
        atomicAdd(&s_acc[r.z >> 16], v2);
        atomicAdd(&s_acc[r.w >> 16], v3);
    }
    if (t < (sz & 3)) {
        const unsigned r = recs_l[(sz4 << 2) + t];
        atomicAdd(&s_acc[r >> 16], zin[r & 0xFFFFu]);
    }
}

// One kernel: bucketize + prep + 3 hops, 4 distributed barriers.
// Block b owns bucket b (nodes [b*196, b*196+196)). z buffers are
// triple-buffered (zA->zB->zC) and 208-padded so cached gathers are safe.
__global__ void __launch_bounds__(NTHR) k_fused(
    const float* __restrict__ x, const int* __restrict__ ei,
    const float* __restrict__ w, const float* __restrict__ bptr,
    float* __restrict__ out,
    unsigned* __restrict__ bars, int* __restrict__ gcur,
    unsigned* __restrict__ recs,
    float* __restrict__ zA, float* __restrict__ zB, float* __restrict__ zC)
{
    __shared__ SmemU u;
    __shared__ int   s_cnt[NBUCK];     // histogram -> gbase -> degree (reused)
    __shared__ int   s_off[NBUCK];
    __shared__ int   s_wsum[4];
    __shared__ int   s_total;
    __shared__ float s_dinv[BRANGE];
    __shared__ float s_z[BRANGE];
    __shared__ float s_acc[BRANGE];

    const int t = threadIdx.x;
    const int blk = blockIdx.x;
    const int* row = ei;               // sources
    const int* col = ei + N_EDGES;     // destinations

    // ---------- phase 1: bucketize (local counting sort) ----------
    if (t < NBUCK) s_cnt[t] = 0;
    __syncthreads();

    const int g = blk * CHUNK + t;
    const bool valid = (t < CHUNK) && (g < EB4);
    int4 c4, r4;
    int bk0, bk1, bk2, bk3, rk0, rk1, rk2, rk3;
    if (valid) {
        c4 = ((const int4*)col)[g];
        r4 = ((const int4*)row)[g];
        bk0 = c4.x / BRANGE; rk0 = atomicAdd(&s_cnt[bk0], 1);
        bk1 = c4.y / BRANGE; rk1 = atomicAdd(&s_cnt[bk1], 1);
        bk2 = c4.z / BRANGE; rk2 = atomicAdd(&s_cnt[bk2], 1);
        bk3 = c4.w / BRANGE; rk3 = atomicAdd(&s_cnt[bk3], 1);
    }

    // raw matvec (X @ W^T, no dinv yet): independent of the sort; issue its
    // loads here to overlap LDS-atomic latency and the scan below.
    const int ln = t >> 2;
    const int pp = t & 3;
    const int node = blk * BRANGE + ln;
    float mv = 0.0f;
    if (ln < BRANGE && node < N_NODES) {
        const float4* xr = (const float4*)(x + (size_t)node * N_FEATS + pp * 16);
        const float4* wr = (const float4*)(w + pp * 16);
        #pragma unroll
        for (int k = 0; k < 4; k++) {
            const float4 v = xr[k];
            const float4 q = wr[k];
            mv += v.x * q.x + v.y * q.y + v.z * q.z + v.w * q.w;
        }
        mv += __shfl_xor(mv, 1);
        mv += __shfl_xor(mv, 2);
    }
    __syncthreads();

    // 256-entry exclusive prefix sum (4 waves, shuffle scan)
    if (t < NBUCK) {
        const int lane = t & 63;
        const int cnt = s_cnt[t];
        int val = cnt;
        #pragma unroll
        for (int d = 1; d < 64; d <<= 1) {
            int tmp = __shfl_up(val, d);
            if (lane >= d) val += tmp;
        }
        if (lane == 63) s_wsum[t >> 6] = val;
        s_off[t] = val - cnt;
    }
    __syncthreads();
    if (t < NBUCK) {
        const int w4 = t >> 6;
        int base = 0;
        #pragma unroll
        for (int i = 0; i < 3; i++) if (i < w4) base += s_wsum[i];
        s_off[t] += base;
        // reserve contiguous global run per bucket (gcur zeroed by host memset)
        const int cnt = s_cnt[t];
        s_cnt[t] = cnt ? atomicAdd(&gcur[t], cnt) : 0;
        if (t == 0) s_total = s_wsum[0] + s_wsum[1] + s_wsum[2] + s_wsum[3];
    }
    __syncthreads();

    // scatter records into LDS bucket-major with final global addresses.
    // Record = (local_dest << 16) | psrc, where psrc = padded z index of the
    // source node: psrc = src + 12*(src/196) < 53060 < 2^16.
    if (valid) {
        const int cc[4] = {c4.x, c4.y, c4.z, c4.w};
        const int rr[4] = {r4.x, r4.y, r4.z, r4.w};
        const int bb[4] = {bk0, bk1, bk2, bk3};
        const int kk[4] = {rk0, rk1, rk2, rk3};
        #pragma unroll
        for (int i = 0; i < 4; i++) {
            const int b = bb[i];
            const int p = s_off[b] + kk[i];
            const int slot = s_cnt[b] + kk[i];
            const unsigned src = (unsigned)rr[i];
            const unsigned psrc = src + 12u * (src / (unsigned)BRANGE);
            u.so.buf[p] = ((unsigned)(cc[i] - b * BRANGE) << 16) | psrc;
            u.so.adr[p] = (slot < CAPB) ? (unsigned)(b * CAPB + slot) : 0xFFFFFFFFu;
        }
    }
    __syncthreads();

    // coalesced stream-out via sc1 stores (fire-and-forget to coherence point)
    const int total = s_total;
    for (int p = t; p < total; p += NTHR) {
        const unsigned a = u.so.adr[p];
        if (a != 0xFFFFFFFFu) st_agent_u(&recs[a], u.so.buf[p]);
    }
    __syncthreads();
    if (t < BRANGE) s_cnt[t] = 0;      // degree counters, zeroed pre-barrier
    if (pp == 0 && ln < BRANGE) s_z[ln] = mv;   // park raw matvec

    gbar(bars, 0);   // all records at coherence point

    // ---------- phase 2: prep (degree + dinv + zA publish) ----------
    const int sz = min((int)ld_agent_u((const unsigned*)&gcur[blk]), CAPB);
    const int sz2 = sz >> 1;           // <= 2048 = 2*NTHR always

    // pull own records into LDS (reused by all 3 hops), degree on the fly.
    // sc1 u64 loads (record lines are written by MANY blocks -> must not be
    // L2-cached). Two independent loads issued back-to-back for ILP.
    {
        const unsigned long long* rb2 =
            (const unsigned long long*)(recs + (size_t)blk * CAPB);
        const bool e0 = t < sz2;
        const bool e1 = t + NTHR < sz2;
        unsigned long long v0 = 0, v1 = 0;
        if (e0) v0 = ld_agent_u64(&rb2[t]);
        if (e1) v1 = ld_agent_u64(&rb2[t + NTHR]);
        if (e0) {
            ((unsigned long long*)u.recs_l)[t] = v0;
            atomicAdd(&s_cnt[((unsigned)v0) >> 16], 1);
            atomicAdd(&s_cnt[((unsigned)(v0 >> 32)) >> 16], 1);
        }
        if (e1) {
            ((unsigned long long*)u.recs_l)[t + NTHR] = v1;
            atomicAdd(&s_cnt[((unsigned)v1) >> 16], 1);
            atomicAdd(&s_cnt[((unsigned)(v1 >> 32)) >> 16], 1);
        }
        if (t == 0 && (sz & 1)) {
            const unsigned r = ld_agent_u(&recs[(size_t)blk * CAPB + sz - 1]);
            u.recs_l[sz - 1] = r;
            atomicAdd(&s_cnt[r >> 16], 1);
        }
    }
    __syncthreads();

    if (t < BRANGE) {
        const float d = rsqrtf((float)(s_cnt[t] + 1));  // +1 self loop
        s_dinv[t] = d;
        const int nd = blk * BRANGE + t;
        if (nd < N_NODES) {
            const float zv = d * s_z[t];
            s_z[t] = zv;                               // own z in LDS
            st_agent(&zA[blk * ZSTRIDE + t], zv);      // publish padded
        }
    }

    gbar(bars, 1);   // zA visible

    // ---------- hop 1: zA -> zB ----------
    if (t < BRANGE) s_acc[t] = 0.0f;
    __syncthreads();
    gather(u.recs_l, sz, zA, s_acc);
    __syncthreads();
    if (t < BRANGE) {
        const int nd = blk * BRANGE + t;
        if (nd < N_NODES) {
            const float d = s_dinv[t];
            const float nz = d * d * (s_z[t] + s_acc[t]);
            s_z[t] = nz;
            st_agent(&zB[blk * ZSTRIDE + t], nz);
        }
    }
    gbar(bars, 2);

    // ---------- hop 2: zB -> zC ----------
    if (t < BRANGE) s_acc[t] = 0.0f;
    __syncthreads();
    gather(u.recs_l, sz, zB, s_acc);
    __syncthreads();
    if (t < BRANGE) {
        const int nd = blk * BRANGE + t;
        if (nd < N_NODES) {
            const float d = s_dinv[t];
            const float nz = d * d * (s_z[t] + s_acc[t]);
            s_z[t] = nz;
            st_agent(&zC[blk * ZSTRIDE + t], nz);
        }
    }
    gbar(bars, 3);

    // ---------- hop 3: zC -> out ----------
    if (t < BRANGE) s_acc[t] = 0.0f;
    __syncthreads();
    gather(u.recs_l, sz, zC, s_acc);
    __syncthreads();
    if (t < BRANGE) {
        const int nd = blk * BRANGE + t;
        if (nd < N_NODES)
            out[nd] = s_dinv[t] * (s_z[t] + s_acc[t]) + bptr[0];
    }
}

// ---------------- launch ----------------

extern "C" void kernel_launch(void* const* d_in, const int* in_sizes, int n_in,
                              void* d_out, int out_size, void* d_ws, size_t ws_size,
                              hipStream_t stream) {
    const float* x  = (const float*)d_in[0];   // [N, 64]
    const int*   ei = (const int*)d_in[1];     // [2, E]
    const float* W  = (const float*)d_in[2];   // [1, 64]
    const float* b  = (const float*)d_in[3];   // [1]
    float* out = (float*)d_out;                // [N]

    // ws: bars[128] | gcur[256] | recs[4 MB] | zA | zB | zC (208-padded)
    unsigned* bars = (unsigned*)d_ws;
    int*      gcur = (int*)(bars + 4 * BARW);
    unsigned* recs = (unsigned*)(gcur + NBUCK);
    float*    zA   = (float*)(recs + (size_t)NBUCK * CAPB);
    float*    zB   = zA + (size_t)NBUCK * ZSTRIDE;
    float*    zC   = zB + (size_t)NBUCK * ZSTRIDE;

    // zero barrier counters + bucket cursors (capture-safe DMA memset)
    hipMemsetAsync(bars, 0, (4 * BARW + NBUCK) * sizeof(unsigned), stream);

    // plain launch: 256 blocks x 16 waves (24 VGPR, ~30 KB LDS) = co-resident
    // on 256 CUs -> spin barrier safe; no cooperative-launch overhead.
    k_fused<<<dim3(NBUCK), dim3(NTHR), 0, stream>>>(
        x, ei, W, b, out, bars, gcur, recs, zA, zB, zC);
}